// Round 3
// baseline (87.325 us; speedup 1.0000x reference)
//
#include <hip/hip_runtime.h>

// EdgeConv2d: B=4, C=64, N=8192, K=16, C_OUT=64
// out[b,o,n] = relu( max_k ( y1[b, i1(b,n,k), o] + y2[b, i0(b,n,k), o] ) + bias[o] )
// y1 = (W[:,:C] - W[:,C:]) @ x[b],  y2 = W[:,C:] @ x[b]
// y layout: y[b][p][n][c2], p = channel-half, c2<32 -> y1[32p+c2], c2>=32 -> y2[32p+c2-32]
// Gather: XCD x (read from HW_REG_XCC_ID) owns slab (b=x>>1, p=x&1) = 2 MB -> its own L2.

#define BB   4
#define CCH  64
#define NN   8192
#define KK   16
#define TILES_PER_SLAB 256          // 8192 nodes / 32 per tile
#define NTILES (8 * TILES_PER_SLAB)

typedef int   v4i __attribute__((ext_vector_type(4)));
typedef float v4f __attribute__((ext_vector_type(4)));

// ---------------------------------------------------------------------------
// Kernel 0: zero claim counters + tile flags (re-run every call).
// ---------------------------------------------------------------------------
__global__ void init_kernel(int* __restrict__ cnt, int* __restrict__ flag) {
    const int t = threadIdx.x + blockIdx.x * blockDim.x;
    if (t < 16) cnt[t] = 0;
    for (int j = t; j < NTILES; j += blockDim.x * gridDim.x) flag[j] = 0;
}

// ---------------------------------------------------------------------------
// Kernel 1: y GEMM. Block: 256 threads, tile = 64 n, all 128 stacked channels.
// ---------------------------------------------------------------------------
__global__ __launch_bounds__(256) void gemm_kernel(const float* __restrict__ x,
                                                   const float* __restrict__ W,
                                                   float* __restrict__ y) {
    __shared__ float wT[64 * 132];   // [k][s] stacked channels, row pad 132
    __shared__ float xs[64 * 64];    // [k][n]

    const int t   = threadIdx.x;
    const int blk = blockIdx.x;               // 512 blocks
    const int xcd  = blk & 7;
    const int b    = xcd >> 1;
    const int tile = ((blk >> 3) << 1) | (xcd & 1);   // 0..127
    const int n0   = tile * 64;

    // Build wT[k][s] in LDS: s<64 -> W1-W2, s>=64 -> W2. Coalesced W-row reads.
    {
        const int sbase = t >> 6;   // uniform per wave
        const int k     = t & 63;   // lane
        #pragma unroll
        for (int i = 0; i < 32; ++i) {
            const int s = sbase + (i << 2);
            float v;
            if (s < CCH) v = W[s * 128 + k] - W[s * 128 + 64 + k];
            else         v = W[(s - CCH) * 128 + 64 + k];
            wT[k * 132 + s] = v;
        }
    }
    // Load x tile [64 k][64 n], coalesced.
    {
        const float* xb = x + (size_t)b * CCH * NN + n0;
        #pragma unroll
        for (int i = 0; i < 16; ++i) {
            const int e = t + (i << 8);
            const int k = e >> 6, n = e & 63;
            xs[k * 64 + n] = xb[(size_t)k * NN + n];
        }
    }
    __syncthreads();

    const int c_grp = t & 31;   // s = 4*c_grp
    const int n_grp = t >> 5;   // n = 8*n_grp .. +7

    float acc[4][8];
    #pragma unroll
    for (int i = 0; i < 4; ++i)
        #pragma unroll
        for (int j = 0; j < 8; ++j) acc[i][j] = 0.f;

    #pragma unroll 8
    for (int k = 0; k < 64; ++k) {
        const float4 wv  = *(const float4*)&wT[k * 132 + 4 * c_grp];
        const float4 xv0 = *(const float4*)&xs[k * 64 + 8 * n_grp];
        const float4 xv1 = *(const float4*)&xs[k * 64 + 8 * n_grp + 4];
        const float wa[4] = {wv.x, wv.y, wv.z, wv.w};
        const float xa[8] = {xv0.x, xv0.y, xv0.z, xv0.w, xv1.x, xv1.y, xv1.z, xv1.w};
        #pragma unroll
        for (int i = 0; i < 4; ++i)
            #pragma unroll
            for (int j = 0; j < 8; ++j)
                acc[i][j] += wa[i] * xa[j];
    }

    // Store into split layout. sg..sg+3 stay within one 32-block -> one float4.
    const int sg = 4 * c_grp;
    int p, c2;
    if (sg < 64) { p = sg >> 5;        c2 = sg & 31; }
    else         { const int c = sg - 64; p = c >> 5; c2 = 32 + (c & 31); }
    float* ybp = y + (((size_t)b * 2 + p) * NN + n0) * 64 + c2;
    #pragma unroll
    for (int j = 0; j < 8; ++j) {
        float4 v;
        v.x = acc[0][j]; v.y = acc[1][j]; v.z = acc[2][j]; v.w = acc[3][j];
        *(float4*)&ybp[(size_t)(8 * n_grp + j) * 64] = v;
    }
}

// ---------------------------------------------------------------------------
// Kernel 2: gather + add + max over K, bias + relu, LDS-transposed store.
// Tile assignment is DYNAMIC: block reads its physical XCD (XCC_ID) and claims
// a tile from that XCD's own 2 MB slab. Flags guarantee exactly-once coverage.
// ---------------------------------------------------------------------------
__global__ __launch_bounds__(256) void gather_kernel(const float* __restrict__ y,
                                                     const int* __restrict__ edge,
                                                     const float* __restrict__ bias,
                                                     float* __restrict__ out,
                                                     int* __restrict__ cnt,
                                                     int* __restrict__ flag) {
    __shared__ float so[32 * 33];   // [n_local][c_local]
    __shared__ int s_j;

    unsigned xcc;
    asm volatile("s_getreg_b32 %0, hwreg(HW_REG_XCC_ID)" : "=s"(xcc));

    if (threadIdx.x == 0) {
        const int x = (int)(xcc & 7u);
        int j = -1;
        const int t = atomicAdd(&cnt[x], 1);
        if (t < TILES_PER_SLAB) {
            const int cand = x * TILES_PER_SLAB + t;
            if (atomicExch(&flag[cand], 1) == 0) j = cand;
        }
        if (j < 0) {  // fallback: steal any unprocessed tile (exactly-once)
            for (int c = 0; c < NTILES; ++c) {
                if (flag[c] == 0 && atomicExch(&flag[c], 1) == 0) { j = c; break; }
            }
        }
        s_j = j;
    }
    __syncthreads();
    const int j = s_j;
    if (j < 0) return;                 // block-uniform

    const int xo   = j >> 8;           // owning slab id
    const int b    = xo >> 1;
    const int p    = xo & 1;
    const int n0   = (j & 255) * 32;

    const int t    = threadIdx.x;
    const int lane = t & 63;
    const int w    = t >> 6;
    const int half = lane >> 5;     // which n of the pair
    const int cl   = lane & 31;     // channel-local 0..31
    const float bv = bias[32 * p + cl];

    const float* yb = y + ((size_t)b * 2 + p) * NN * 64;
    const int* e0base = edge + (size_t)b * NN * KK;          // neighbors j
    const int* e1base = edge + (size_t)(BB + b) * NN * KK;   // centers i

    #pragma unroll
    for (int jj = 0; jj < 4; ++jj) {
        const int n_x = n0 + 8 * w + 2 * jj + half;          // uniform per half-wave
        const v4i* e0 = (const v4i*)(e0base + (size_t)n_x * KK);
        const v4i* e1 = (const v4i*)(e1base + (size_t)n_x * KK);
        float acc = -3.4e38f;
        #pragma unroll
        for (int q = 0; q < 4; ++q) {
            const v4i i0v = __builtin_nontemporal_load(e0 + q);
            const v4i i1v = __builtin_nontemporal_load(e1 + q);
            acc = fmaxf(acc, yb[(size_t)i1v.x * 64 + cl] + yb[(size_t)i0v.x * 64 + 32 + cl]);
            acc = fmaxf(acc, yb[(size_t)i1v.y * 64 + cl] + yb[(size_t)i0v.y * 64 + 32 + cl]);
            acc = fmaxf(acc, yb[(size_t)i1v.z * 64 + cl] + yb[(size_t)i0v.z * 64 + 32 + cl]);
            acc = fmaxf(acc, yb[(size_t)i1v.w * 64 + cl] + yb[(size_t)i0v.w * 64 + 32 + cl]);
        }
        so[(8 * w + 2 * jj + half) * 33 + cl] = fmaxf(acc + bv, 0.f);
    }
    __syncthreads();

    // Transposed, coalesced, non-temporal store: out[b][32p + c][n0 + 4q + r]
    {
        const int c = t >> 3;       // 0..31
        const int q = t & 7;        // 0..7
        v4f v;
        v.x = so[(4 * q + 0) * 33 + c];
        v.y = so[(4 * q + 1) * 33 + c];
        v.z = so[(4 * q + 2) * 33 + c];
        v.w = so[(4 * q + 3) * 33 + c];
        float* ob = out + ((size_t)b * CCH + 32 * p + c) * NN + n0;
        __builtin_nontemporal_store(v, (v4f*)&ob[4 * q]);
    }
}

extern "C" void kernel_launch(void* const* d_in, const int* in_sizes, int n_in,
                              void* d_out, int out_size, void* d_ws, size_t ws_size,
                              hipStream_t stream) {
    (void)in_sizes; (void)n_in; (void)out_size; (void)ws_size;
    const float* x    = (const float*)d_in[0];
    const int*   edge = (const int*)d_in[1];
    const float* W    = (const float*)d_in[2];
    const float* bias = (const float*)d_in[3];
    float*       out  = (float*)d_out;
    float*       y    = (float*)d_ws;                          // 16 MB
    int*         cnt  = (int*)((char*)d_ws + (16u << 20));     // 16 ints
    int*         flag = cnt + 16;                              // 2048 ints

    init_kernel<<<dim3(8), dim3(256), 0, stream>>>(cnt, flag);
    gemm_kernel<<<dim3(512), dim3(256), 0, stream>>>(x, W, y);
    gather_kernel<<<dim3(2048), dim3(256), 0, stream>>>(y, edge, bias, out, cnt, flag);
}

// Round 4
// 27.993 us; speedup vs baseline: 3.1195x; 3.1195x over previous
//
#include <hip/hip_runtime.h>

// EdgeConv2d: B=4, C=64, N=8192, K=16, C_OUT=64
// out[b,o,n] = relu( max_k ( y1[b, i1(b,n,k), o] + y2[b, i0(b,n,k), o] ) + bias[o] )
// y1 = (W[:,:C] - W[:,C:]) @ x[b],  y2 = W[:,C:] @ x[b]
// y (fp16): y[b][n][s], s<64 -> y1[s], s>=64 -> y2[s-64].  Row = 256 B.

#define BB   4
#define CCH  64
#define NN   8192
#define KK   16

typedef _Float16 h2 __attribute__((ext_vector_type(2)));
typedef _Float16 h4 __attribute__((ext_vector_type(4)));

__global__ __launch_bounds__(256) void gemm_kernel(const float* __restrict__ x,
                                                   const float* __restrict__ W,
                                                   _Float16* __restrict__ y) {
    __shared__ float wT[64 * 132];
    __shared__ float xs[64 * 64];

    const int t   = threadIdx.x;
    const int blk = blockIdx.x;               // 512 blocks
    const int xcd  = blk & 7;
    const int b    = xcd >> 1;
    const int tile = ((blk >> 3) << 1) | (xcd & 1);   // 0..127
    const int n0   = tile * 64;

    {
        const int sbase = t >> 6;
        const int k     = t & 63;
        #pragma unroll
        for (int i = 0; i < 32; ++i) {
            const int s = sbase + (i << 2);
            float v;
            if (s < CCH) v = W[s * 128 + k] - W[s * 128 + 64 + k];
            else         v = W[(s - CCH) * 128 + 64 + k];
            wT[k * 132 + s] = v;
        }
    }
    {
        const float* xb = x + (size_t)b * CCH * NN + n0;
        #pragma unroll
        for (int i = 0; i < 16; ++i) {
            const int e = t + (i << 8);
            const int k = e >> 6, n = e & 63;
            xs[k * 64 + n] = xb[(size_t)k * NN + n];
        }
    }
    __syncthreads();

    const int c_grp = t & 31;
    const int n_grp = t >> 5;

    float acc[4][8];
    #pragma unroll
    for (int i = 0; i < 4; ++i)
        #pragma unroll
        for (int j = 0; j < 8; ++j) acc[i][j] = 0.f;

    #pragma unroll 8
    for (int k = 0; k < 64; ++k) {
        const float4 wv  = *(const float4*)&wT[k * 132 + 4 * c_grp];
        const float4 xv0 = *(const float4*)&xs[k * 64 + 8 * n_grp];
        const float4 xv1 = *(const float4*)&xs[k * 64 + 8 * n_grp + 4];
        const float wa[4] = {wv.x, wv.y, wv.z, wv.w};
        const float xa[8] = {xv0.x, xv0.y, xv0.z, xv0.w, xv1.x, xv1.y, xv1.z, xv1.w};
        #pragma unroll
        for (int i = 0; i < 4; ++i)
            #pragma unroll
            for (int j = 0; j < 8; ++j)
                acc[i][j] += wa[i] * xa[j];
    }

    _Float16* ybp = y + ((size_t)b * NN + n0) * 128 + 4 * c_grp;
    #pragma unroll
    for (int j = 0; j < 8; ++j) {
        h4 v;
        v.x = (_Float16)acc[0][j]; v.y = (_Float16)acc[1][j];
        v.z = (_Float16)acc[2][j]; v.w = (_Float16)acc[3][j];
        *(h4*)&ybp[(size_t)(8 * n_grp + j) * 128] = v;
    }
}

__global__ __launch_bounds__(256) void gather_kernel(const _Float16* __restrict__ y,
                                                     const int* __restrict__ edge,
                                                     const float* __restrict__ bias,
                                                     float* __restrict__ out) {
    __shared__ int   eL[16][2][16];   // [nl][src][k] src0=e1(center->y1), src1=e0(->y2)
    __shared__ float so[16][65];

    const int t   = threadIdx.x;
    const int blk = blockIdx.x;       // 2048
    const int xcd  = blk & 7;
    const int b    = xcd >> 1;
    const int tile = ((blk >> 3) << 1) | (xcd & 1);   // 0..511
    const int n0   = tile * 16;

    if (t < 128) {
        const int src = t >> 6;                 // 0 -> e1, 1 -> e0
        const int f   = (t & 63) << 2;
        const int nl  = f >> 4, k0 = f & 15;
        const size_t eb = (size_t)(src == 0 ? BB + b : b) * NN * KK;
        *(int4*)&eL[nl][src][k0] = *(const int4*)&edge[eb + (size_t)(n0 + nl) * KK + k0];
    }
    __syncthreads();

    const int w    = t >> 6;
    const int lane = t & 63;
    const int half = lane >> 5;       // which k of each pair
    const int cl   = lane & 31;       // channel pair: {2cl, 2cl+1}

    const float2 bv = *(const float2*)&bias[2 * cl];
    const _Float16* yb = y + (size_t)b * NN * 128;

    #pragma unroll 2
    for (int u = 0; u < 4; ++u) {
        const int nl = 4 * w + u;
        h2 s[8];
        #pragma unroll
        for (int kp = 0; kp < 8; ++kp) {
            const int k  = 2 * kp + half;
            const int i1 = eL[nl][0][k];
            const int i0 = eL[nl][1][k];
            const uint a = *(const uint*)&yb[(size_t)i1 * 128 + 2 * cl];       // y1
            const uint c = *(const uint*)&yb[(size_t)i0 * 128 + 64 + 2 * cl];  // y2
            union { uint u32; h2 h; } ua, uc;
            ua.u32 = a; uc.u32 = c;
            s[kp] = ua.h + uc.h;                // v_pk_add_f16
        }
        h2 m = s[0];
        #pragma unroll
        for (int kp = 1; kp < 8; ++kp) m = __builtin_elementwise_max(m, s[kp]);
        union { int i32; h2 h; } um, uo;
        um.h = m;
        uo.i32 = __shfl_xor(um.i32, 32, 64);
        m = __builtin_elementwise_max(m, uo.h);
        if (half == 0) {
            float2 r;
            r.x = fmaxf((float)m.x + bv.x, 0.f);
            r.y = fmaxf((float)m.y + bv.y, 0.f);
            *(float2*)&so[nl][2 * cl] = r;
        }
    }
    __syncthreads();

    {
        const int c = t >> 2;
        const int q = t & 3;
        float4 v;
        v.x = so[4 * q + 0][c];
        v.y = so[4 * q + 1][c];
        v.z = so[4 * q + 2][c];
        v.w = so[4 * q + 3][c];
        *(float4*)(out + ((size_t)b * CCH + c) * NN + n0 + 4 * q) = v;
    }
}

extern "C" void kernel_launch(void* const* d_in, const int* in_sizes, int n_in,
                              void* d_out, int out_size, void* d_ws, size_t ws_size,
                              hipStream_t stream) {
    (void)in_sizes; (void)n_in; (void)out_size; (void)ws_size;
    const float* x    = (const float*)d_in[0];
    const int*   edge = (const int*)d_in[1];
    const float* W    = (const float*)d_in[2];
    const float* bias = (const float*)d_in[3];
    float*       out  = (float*)d_out;
    _Float16*    y    = (_Float16*)d_ws;    // [B][N][128] fp16 = 8 MB

    gemm_kernel<<<dim3(512), dim3(256), 0, stream>>>(x, W, y);
    gather_kernel<<<dim3(2048), dim3(256), 0, stream>>>(y, edge, bias, out);
}